// Round 4
// baseline (679.760 us; speedup 1.0000x reference)
//
#include <hip/hip_runtime.h>
#include <hip/hip_bf16.h>

#define SEQ   512
#define BATCH 256
#define ZD    64

typedef float vfloat2 __attribute__((ext_vector_type(2)));
typedef float vfloat4 __attribute__((ext_vector_type(4)));

__device__ __forceinline__ int lane_bcasti(int v, int i) {
  return __builtin_amdgcn_readlane(v, i);
}

// Broadcast alpha[i] to all lanes via ds_bpermute with a uniform index:
// vz is an opaque zero VGPR; the backend folds (vz + 4*i) into the DS
// offset: field -> one shared index register, 64 instructions with
// compile-time offsets. Result lands in a VGPR (no SGPR hazard), ops are
// mutually independent (pipelined on the DS pipe).
__device__ __forceinline__ float bperm_bcast(int vz, int src_bits, int i) {
  return __int_as_float(__builtin_amdgcn_ds_bpermute(vz + 4 * i, src_bits));
}

// 16 group names 00..17 (octal, 0##n = 0..15). Group n covers broadcast
// indices 4n..4n+3: pair ua##n multiplies (4n,4n+1) into acc01, pair ub##n
// multiplies (4n+2,4n+3) into acc23. v_pk_fma_f32 halves = two independent
// fmaf -> reproduces the original acc[i&3] 4-chain order bit-exactly.
#define REP8(M,p)  M(p##0) M(p##1) M(p##2) M(p##3) M(p##4) M(p##5) M(p##6) M(p##7)
#define REP16(M)   REP8(M,0) REP8(M,1)

#define UDECL(n)  vfloat2 ua##n, ub##n;
#define ULOADF(n) ua##n = *(const vfloat2*)(Trp + 4*(0##n)); \
                  ub##n = *(const vfloat2*)(Trp + 4*(0##n) + 2);
#define ULOADB(n) ua##n = (vfloat2){Tcp[(4*(0##n)+0)*ZD], Tcp[(4*(0##n)+1)*ZD]}; \
                  ub##n = (vfloat2){Tcp[(4*(0##n)+2)*ZD], Tcp[(4*(0##n)+3)*ZD]};
#define UFMA(n)   { const float r0 = bperm_bcast(vz, vbc_bits, 4*(0##n)+0); \
                    const float r1 = bperm_bcast(vz, vbc_bits, 4*(0##n)+1); \
                    const float r2 = bperm_bcast(vz, vbc_bits, 4*(0##n)+2); \
                    const float r3 = bperm_bcast(vz, vbc_bits, 4*(0##n)+3); \
                    acc01 = __builtin_elementwise_fma((vfloat2){r0, r1}, ua##n, acc01); \
                    acc23 = __builtin_elementwise_fma((vfloat2){r2, r3}, ub##n, acc23); }
// Opaque register pin: stops LICM from re-sinking the T loads into the loop.
#define UPIN(p)   asm volatile("" : "+v"(ua##p##0), "+v"(ua##p##1), "+v"(ua##p##2), \
                                    "+v"(ua##p##3), "+v"(ua##p##4), "+v"(ua##p##5), \
                                    "+v"(ua##p##6), "+v"(ua##p##7), \
                                    "+v"(ub##p##0), "+v"(ub##p##1), "+v"(ub##p##2), \
                                    "+v"(ub##p##3), "+v"(ub##p##4), "+v"(ub##p##5), \
                                    "+v"(ub##p##6), "+v"(ub##p##7));
#define UPIN_ALL  UPIN(0) UPIN(1)

// One wave (64 lanes = 64 z-states) per chain; blocks 0..255 forward,
// 256..511 backward.
//
// Round-by-round evidence on the serial step (632 cyc measured at best):
//  - memory reordering / NT / prefetch: no effect (rounds 0-2) -> not memory.
//  - LDS write->read broadcast + pk_fma: VALUBusy 32->9% but 947 cyc/step
//    (round 3) -> serial LDS round-trip latency is fatal; ops-count isn't
//    the limiter.
//  => bottleneck is the 64x v_readlane->SGPR->v_fma wait-state chain.
// Round 4: broadcast via 64 INDEPENDENT ds_bpermute (uniform index, offset
// folded) -> VGPR results, no SGPR hazard, pipelined on the DS pipe while
// the VALU runs 32 v_pk_fma_f32. No serial LDS dependency (unlike round 3:
// these reads depend only on alpha already in registers).
__global__ __launch_bounds__(64, 1) void hmm_chains(
    const int*   __restrict__ inp,    // [SEQ, BATCH]
    const float* __restrict__ T,      // [ZD, ZD] row-major
    const float* __restrict__ pi,     // [ZD]
    const float* __restrict__ emit,   // [X, ZD]
    float* __restrict__ out_alpha,    // [SEQ, BATCH, ZD] fp32
    float* __restrict__ out_beta)     // [SEQ, BATCH, ZD] fp32
{
  const int lane = threadIdx.x;
  const int blk  = blockIdx.x;
  const bool fwd = (blk < BATCH);
  const int b    = fwd ? blk : blk - BATCH;

  int vz = 0;
  asm volatile("" : "+v"(vz));        // opaque zero -> shared bpermute index

  REP16(UDECL)

  if (fwd) {
    // Shifted x registers: xvn[w] lane l = x[min(64w+l+1, 511)] so the
    // in-iter prefetch index x[t+1] is a single readlane.
    int xvn[8];
    #pragma unroll
    for (int w = 0; w < 8; ++w) {
      int li = w * 64 + lane + 1;
      if (li > SEQ - 1) li = SEQ - 1;
      xvn[w] = inp[li * BATCH + b];
    }

    // alpha_t[l] = e_t[l] * sum_i alpha_{t-1}[i] * T[l][i]
    const float* Trp = T + lane * ZD;
    REP16(ULOADF)
    UPIN_ALL

    const int x0 = inp[b];                   // x[0], uniform scalar load
    float alpha = emit[x0 * ZD + lane] * pi[lane];
    float* op = out_alpha + (size_t)b * ZD + lane;

    const int x1 = lane_bcasti(xvn[0], 0);
    float e_cur = emit[x1 * ZD + lane];      // e_1
    *op = alpha;
    op += BATCH * ZD;

    #pragma unroll
    for (int w = 0; w < 8; ++w) {
      const int xnw = xvn[w];
      #pragma unroll 1                 // keep body small, inside L1I
      for (int idx = (w == 0) ? 1 : 0; idx < 64; ++idx) {
        const int   xt1  = lane_bcasti(xnw, idx);   // x[t+1] (uniform)
        const float e_pf = emit[xt1 * ZD + lane];   // used next iter
        const int vbc_bits = __float_as_int(alpha);
        vfloat2 acc01 = {0.f, 0.f}, acc23 = {0.f, 0.f};
        REP16(UFMA)                        // 64 bpermute + 32 pk_fma
        alpha = e_cur * ((acc01.x + acc01.y) + (acc23.x + acc23.y));
        *op = alpha;
        op += BATCH * ZD;
        e_cur = e_pf;
      }
    }
  } else {
    // beta_t[l] = sum_j (e_{t+1}[j]*beta_{t+1}[j]) * T[j][l]
    int xv[8];
    #pragma unroll
    for (int w = 0; w < 8; ++w)
      xv[w] = inp[(w * 64 + lane) * BATCH + b];

    const float* Tcp = T + lane;
    REP16(ULOADB)
    UPIN_ALL

    float beta = 1.0f;
    float* op = out_beta + ((size_t)(SEQ - 1) * BATCH + b) * ZD + lane;
    *op = beta;
    op -= BATCH * ZD;

    const int xL = lane_bcasti(xv[7], 63);
    float e_next = emit[xL * ZD + lane];          // e_{511}, consumed at t=510

    #pragma unroll
    for (int w = 7; w >= 0; --w) {
      const int xvw = xv[w];
      #pragma unroll 1
      for (int idx = (w == 7) ? 62 : 63; idx >= 0; --idx) {
        const int   xt   = lane_bcasti(xvw, idx); // x_t, e for next iteration
        const float e_pf = emit[xt * ZD + lane];  // used next iter
        const float g    = e_next * beta;         // broadcast source g[j]
        const int vbc_bits = __float_as_int(g);
        vfloat2 acc01 = {0.f, 0.f}, acc23 = {0.f, 0.f};
        REP16(UFMA)
        beta = (acc01.x + acc01.y) + (acc23.x + acc23.y);
        *op = beta;
        op -= BATCH * ZD;
        e_next = e_pf;
      }
    }
  }
}

// posterior[t,b,z] = alpha*beta / sum_z(alpha*beta). 8 z per lane (2x vfloat4),
// 8 lanes per (t,b) row, xor-shuffle reduction within the 8-lane group.
// Plain (cached) loads: alpha/beta were just written -> L2/L3 resident.
__global__ __launch_bounds__(256) void posterior_k(
    const float* __restrict__ a,
    const float* __restrict__ bt,
    float*       __restrict__ p)
{
  const int tid = blockIdx.x * 256 + threadIdx.x;
  const size_t base = (size_t)tid * 8;

  const vfloat4 va0 = *reinterpret_cast<const vfloat4*>(a  + base);
  const vfloat4 va1 = *reinterpret_cast<const vfloat4*>(a  + base + 4);
  const vfloat4 vb0 = *reinterpret_cast<const vfloat4*>(bt + base);
  const vfloat4 vb1 = *reinterpret_cast<const vfloat4*>(bt + base + 4);

  const float p0 = va0.x * vb0.x;
  const float p1 = va0.y * vb0.y;
  const float p2 = va0.z * vb0.z;
  const float p3 = va0.w * vb0.w;
  const float p4 = va1.x * vb1.x;
  const float p5 = va1.y * vb1.y;
  const float p6 = va1.z * vb1.z;
  const float p7 = va1.w * vb1.w;

  float s = ((p0 + p1) + (p2 + p3)) + ((p4 + p5) + (p6 + p7));
  s += __shfl_xor(s, 1);
  s += __shfl_xor(s, 2);
  s += __shfl_xor(s, 4);
  const float inv = 1.0f / s;

  vfloat4 o0, o1;
  o0.x = p0 * inv; o0.y = p1 * inv; o0.z = p2 * inv; o0.w = p3 * inv;
  o1.x = p4 * inv; o1.y = p5 * inv; o1.z = p6 * inv; o1.w = p7 * inv;
  *reinterpret_cast<vfloat4*>(p + base)     = o0;
  *reinterpret_cast<vfloat4*>(p + base + 4) = o1;
}

extern "C" void kernel_launch(void* const* d_in, const int* in_sizes, int n_in,
                              void* d_out, int out_size, void* d_ws, size_t ws_size,
                              hipStream_t stream) {
  const int*   inp  = (const int*)  d_in[0];
  const float* T    = (const float*)d_in[1];
  const float* pi   = (const float*)d_in[2];
  const float* emit = (const float*)d_in[3];

  float* out = (float*)d_out;
  const size_t N = (size_t)SEQ * BATCH * ZD;   // 8388608 per output
  float* out_alpha = out;
  float* out_beta  = out + N;
  float* out_post  = out + 2 * N;

  hipLaunchKernelGGL(hmm_chains, dim3(2 * BATCH), dim3(64), 0, stream,
                     inp, T, pi, emit, out_alpha, out_beta);

  hipLaunchKernelGGL(posterior_k, dim3((unsigned)(N / 2048)), dim3(256), 0, stream,
                     out_alpha, out_beta, out_post);
}

// Round 5
// 257.597 us; speedup vs baseline: 2.6388x; 2.6388x over previous
//
#include <hip/hip_runtime.h>
#include <hip/hip_bf16.h>

#define SEQ   512
#define BATCH 256
#define ZD    64

typedef float vfloat4 __attribute__((ext_vector_type(4)));

__device__ __forceinline__ int lane_bcasti(int v, int i) {
  return __builtin_amdgcn_readlane(v, i);
}

// 64 distinct scalar names t00..t77 (two octal digits). The literal 0##n is
// an OCTAL constant equal to the linear index: t45 <-> 045 = 4*8+5 = 37.
#define REP8(M,p)  M(p##0) M(p##1) M(p##2) M(p##3) M(p##4) M(p##5) M(p##6) M(p##7)
#define REP64(M)   REP8(M,0) REP8(M,1) REP8(M,2) REP8(M,3) \
                   REP8(M,4) REP8(M,5) REP8(M,6) REP8(M,7)

#define TDECL(n)  float t##n;
#define TLOADF(n) t##n = Trp[0##n];          // T[lane][i], i = 0##n
#define TLOADB(n) t##n = Tcp[(0##n) * ZD];   // T[j][lane], j = 0##n
// Opaque register pin: stops LICM from re-sinking the T loads into the loop.
#define TPIN(p)   asm volatile("" : "+v"(t##p##0), "+v"(t##p##1), "+v"(t##p##2), \
                                    "+v"(t##p##3), "+v"(t##p##4), "+v"(t##p##5), \
                                    "+v"(t##p##6), "+v"(t##p##7));
#define TPIN_ALL  TPIN(0) TPIN(1) TPIN(2) TPIN(3) TPIN(4) TPIN(5) TPIN(6) TPIN(7)

// Round 8: SGPR de-recycling. Evidence: 632 cyc/step vs 256-cyc issue floor;
// memory ordering no effect (R0-2); LDS broadcast 947 cyc (R3); bpermute
// 2700 cyc (R4). Remaining mechanism: with fma(readlane(i), t_i, acc)
// emitted pairwise, regalloc reuses 1-2 SGPRs for all 64 readlane results ->
// per pair: readlane writes s0, VALU-writes-SGPR->VALU-reads-SGPR hazard
// (~2-4 cyc), fma reads s0, next readlane stuck behind the stalled fma
// (in-order issue). ~6 cyc/pair * 64 = the ~380 missing cycles.
// Fix: batch 16 readlanes into named ints pinned "+s" (forces 16 live SGPRs),
// then 16 FMAs. First FMA's SGPR was written 15 instrs earlier -> no hazard;
// groups are mutually independent -> scheduler can interleave.
// Accumulation order i ascending into acc[i&3]: BIT-IDENTICAL to baseline.
#define BCGROUP(pa, pb) { \
  int q0 = lane_bcasti(vbc_bits, 0##pa##0); \
  int q1 = lane_bcasti(vbc_bits, 0##pa##1); \
  int q2 = lane_bcasti(vbc_bits, 0##pa##2); \
  int q3 = lane_bcasti(vbc_bits, 0##pa##3); \
  int q4 = lane_bcasti(vbc_bits, 0##pa##4); \
  int q5 = lane_bcasti(vbc_bits, 0##pa##5); \
  int q6 = lane_bcasti(vbc_bits, 0##pa##6); \
  int q7 = lane_bcasti(vbc_bits, 0##pa##7); \
  int q8 = lane_bcasti(vbc_bits, 0##pb##0); \
  int q9 = lane_bcasti(vbc_bits, 0##pb##1); \
  int qa = lane_bcasti(vbc_bits, 0##pb##2); \
  int qb = lane_bcasti(vbc_bits, 0##pb##3); \
  int qc = lane_bcasti(vbc_bits, 0##pb##4); \
  int qd = lane_bcasti(vbc_bits, 0##pb##5); \
  int qe = lane_bcasti(vbc_bits, 0##pb##6); \
  int qf = lane_bcasti(vbc_bits, 0##pb##7); \
  asm volatile("" : "+s"(q0),"+s"(q1),"+s"(q2),"+s"(q3), \
                    "+s"(q4),"+s"(q5),"+s"(q6),"+s"(q7), \
                    "+s"(q8),"+s"(q9),"+s"(qa),"+s"(qb), \
                    "+s"(qc),"+s"(qd),"+s"(qe),"+s"(qf)); \
  acc[0] = fmaf(__int_as_float(q0), t##pa##0, acc[0]); \
  acc[1] = fmaf(__int_as_float(q1), t##pa##1, acc[1]); \
  acc[2] = fmaf(__int_as_float(q2), t##pa##2, acc[2]); \
  acc[3] = fmaf(__int_as_float(q3), t##pa##3, acc[3]); \
  acc[0] = fmaf(__int_as_float(q4), t##pa##4, acc[0]); \
  acc[1] = fmaf(__int_as_float(q5), t##pa##5, acc[1]); \
  acc[2] = fmaf(__int_as_float(q6), t##pa##6, acc[2]); \
  acc[3] = fmaf(__int_as_float(q7), t##pa##7, acc[3]); \
  acc[0] = fmaf(__int_as_float(q8), t##pb##0, acc[0]); \
  acc[1] = fmaf(__int_as_float(q9), t##pb##1, acc[1]); \
  acc[2] = fmaf(__int_as_float(qa), t##pb##2, acc[2]); \
  acc[3] = fmaf(__int_as_float(qb), t##pb##3, acc[3]); \
  acc[0] = fmaf(__int_as_float(qc), t##pb##4, acc[0]); \
  acc[1] = fmaf(__int_as_float(qd), t##pb##5, acc[1]); \
  acc[2] = fmaf(__int_as_float(qe), t##pb##6, acc[2]); \
  acc[3] = fmaf(__int_as_float(qf), t##pb##7, acc[3]); }

#define BC_ALL  BCGROUP(0,1) BCGROUP(2,3) BCGROUP(4,5) BCGROUP(6,7)

// One wave (64 lanes = 64 z-states) per chain; blocks 0..255 forward,
// 256..511 backward. No LDS, no barriers.
__global__ __launch_bounds__(64, 1) void hmm_chains(
    const int*   __restrict__ inp,    // [SEQ, BATCH]
    const float* __restrict__ T,      // [ZD, ZD] row-major
    const float* __restrict__ pi,     // [ZD]
    const float* __restrict__ emit,   // [X, ZD]
    float* __restrict__ out_alpha,    // [SEQ, BATCH, ZD] fp32
    float* __restrict__ out_beta)     // [SEQ, BATCH, ZD] fp32
{
  const int lane = threadIdx.x;
  const int blk  = blockIdx.x;
  const bool fwd = (blk < BATCH);
  const int b    = fwd ? blk : blk - BATCH;

  REP64(TDECL)

  if (fwd) {
    // Shifted x registers: xvn[w] lane l = x[min(64w+l+1, 511)] so the
    // in-iter prefetch index x[t+1] is a single readlane.
    int xvn[8];
    #pragma unroll
    for (int w = 0; w < 8; ++w) {
      int li = w * 64 + lane + 1;
      if (li > SEQ - 1) li = SEQ - 1;
      xvn[w] = inp[li * BATCH + b];
    }

    // alpha_t[l] = e_t[l] * sum_i alpha_{t-1}[i] * T[l][i]
    const float* Trp = T + lane * ZD;
    REP64(TLOADF)
    TPIN_ALL

    const int x0 = inp[b];                   // x[0], uniform scalar load
    float alpha = emit[x0 * ZD + lane] * pi[lane];
    float* op = out_alpha + (size_t)b * ZD + lane;

    const int x1 = lane_bcasti(xvn[0], 0);
    float e_cur = emit[x1 * ZD + lane];      // e_1
    __builtin_nontemporal_store(alpha, op);
    op += BATCH * ZD;

    #pragma unroll
    for (int w = 0; w < 8; ++w) {
      const int xnw = xvn[w];
      #pragma unroll 1                 // keep body inside L1I
      for (int idx = (w == 0) ? 1 : 0; idx < 64; ++idx) {
        const int   xt1  = lane_bcasti(xnw, idx);   // x[t+1] (uniform)
        const float e_pf = emit[xt1 * ZD + lane];   // used next iter
        const int vbc_bits = __float_as_int(alpha);
        float acc[4] = {0.f, 0.f, 0.f, 0.f};
        BC_ALL                                      // 4x (16 readlane ; 16 fma)
        alpha = e_cur * ((acc[0] + acc[1]) + (acc[2] + acc[3]));
        __builtin_nontemporal_store(alpha, op);
        op += BATCH * ZD;
        e_cur = e_pf;
      }
    }
  } else {
    // beta_t[l] = sum_j (e_{t+1}[j]*beta_{t+1}[j]) * T[j][l]
    int xv[8];
    #pragma unroll
    for (int w = 0; w < 8; ++w)
      xv[w] = inp[(w * 64 + lane) * BATCH + b];

    const float* Tcp = T + lane;
    REP64(TLOADB)
    TPIN_ALL

    float beta = 1.0f;
    float* op = out_beta + ((size_t)(SEQ - 1) * BATCH + b) * ZD + lane;
    __builtin_nontemporal_store(beta, op);
    op -= BATCH * ZD;

    const int xL = lane_bcasti(xv[7], 63);
    float e_next = emit[xL * ZD + lane];          // e_{511}, consumed at t=510

    #pragma unroll
    for (int w = 7; w >= 0; --w) {
      const int xvw = xv[w];
      #pragma unroll 1
      for (int idx = (w == 7) ? 62 : 63; idx >= 0; --idx) {
        const int   xt   = lane_bcasti(xvw, idx); // x_t, e for next iteration
        const float e_pf = emit[xt * ZD + lane];  // used next iter
        const float g    = e_next * beta;         // broadcast source g[j]
        const int vbc_bits = __float_as_int(g);
        float acc[4] = {0.f, 0.f, 0.f, 0.f};
        BC_ALL
        beta = (acc[0] + acc[1]) + (acc[2] + acc[3]);
        __builtin_nontemporal_store(beta, op);
        op -= BATCH * ZD;
        e_next = e_pf;
      }
    }
  }
}

// posterior[t,b,z] = alpha*beta / sum_z(alpha*beta). 8 z per lane (2x vfloat4),
// 8 lanes per (t,b) row, xor-shuffle reduction within the 8-lane group.
__global__ __launch_bounds__(256) void posterior_k(
    const float* __restrict__ a,
    const float* __restrict__ bt,
    float*       __restrict__ p)
{
  const int tid = blockIdx.x * 256 + threadIdx.x;
  const size_t base = (size_t)tid * 8;

  const vfloat4 va0 = *reinterpret_cast<const vfloat4*>(a  + base);
  const vfloat4 va1 = *reinterpret_cast<const vfloat4*>(a  + base + 4);
  const vfloat4 vb0 = *reinterpret_cast<const vfloat4*>(bt + base);
  const vfloat4 vb1 = *reinterpret_cast<const vfloat4*>(bt + base + 4);

  const float p0 = va0.x * vb0.x;
  const float p1 = va0.y * vb0.y;
  const float p2 = va0.z * vb0.z;
  const float p3 = va0.w * vb0.w;
  const float p4 = va1.x * vb1.x;
  const float p5 = va1.y * vb1.y;
  const float p6 = va1.z * vb1.z;
  const float p7 = va1.w * vb1.w;

  float s = ((p0 + p1) + (p2 + p3)) + ((p4 + p5) + (p6 + p7));
  s += __shfl_xor(s, 1);
  s += __shfl_xor(s, 2);
  s += __shfl_xor(s, 4);
  const float inv = 1.0f / s;

  vfloat4 o0, o1;
  o0.x = p0 * inv; o0.y = p1 * inv; o0.z = p2 * inv; o0.w = p3 * inv;
  o1.x = p4 * inv; o1.y = p5 * inv; o1.z = p6 * inv; o1.w = p7 * inv;
  *reinterpret_cast<vfloat4*>(p + base)     = o0;
  *reinterpret_cast<vfloat4*>(p + base + 4) = o1;
}

extern "C" void kernel_launch(void* const* d_in, const int* in_sizes, int n_in,
                              void* d_out, int out_size, void* d_ws, size_t ws_size,
                              hipStream_t stream) {
  const int*   inp  = (const int*)  d_in[0];
  const float* T    = (const float*)d_in[1];
  const float* pi   = (const float*)d_in[2];
  const float* emit = (const float*)d_in[3];

  float* out = (float*)d_out;
  const size_t N = (size_t)SEQ * BATCH * ZD;   // 8388608 per output
  float* out_alpha = out;
  float* out_beta  = out + N;
  float* out_post  = out + 2 * N;

  hipLaunchKernelGGL(hmm_chains, dim3(2 * BATCH), dim3(64), 0, stream,
                     inp, T, pi, emit, out_alpha, out_beta);

  hipLaunchKernelGGL(posterior_k, dim3((unsigned)(N / 2048)), dim3(256), 0, stream,
                     out_alpha, out_beta, out_post);
}

// Round 7
// 247.820 us; speedup vs baseline: 2.7430x; 1.0395x over previous
//
#include <hip/hip_runtime.h>
#include <hip/hip_bf16.h>

#define SEQ   512
#define BATCH 256
#define ZD    64

__device__ __forceinline__ float lane_bcastf(float v, int i) {
  return __int_as_float(__builtin_amdgcn_readlane(__float_as_int(v), i));
}
__device__ __forceinline__ int lane_bcasti(int v, int i) {
  return __builtin_amdgcn_readlane(v, i);
}

// 64 distinct scalar names t00..t77 (two octal digits). The literal 0##n is
// an OCTAL constant equal to the linear index: t45 <-> 045 = 4*8+5 = 37.
#define REP8(M,p)  M(p##0) M(p##1) M(p##2) M(p##3) M(p##4) M(p##5) M(p##6) M(p##7)
#define REP64(M)   REP8(M,0) REP8(M,1) REP8(M,2) REP8(M,3) \
                   REP8(M,4) REP8(M,5) REP8(M,6) REP8(M,7)

#define TDECL(n)  float t##n;
#define TLOADF(n) t##n = Trp[0##n];          // T[lane][i], i = 0##n
#define TLOADB(n) t##n = Tcp[(0##n) * ZD];   // T[j][lane], j = 0##n
// Accumulate into 4 chains (constant index -> SROA keeps acc in registers).
#define TFMA(n)   acc[(0##n) & 3] = fmaf(lane_bcastf(vbc, 0##n), t##n, acc[(0##n) & 3]);
// Opaque register pin: stops LICM from re-sinking the T loads into the loop.
#define TPIN(p)   asm volatile("" : "+v"(t##p##0), "+v"(t##p##1), "+v"(t##p##2), \
                                    "+v"(t##p##3), "+v"(t##p##4), "+v"(t##p##5), \
                                    "+v"(t##p##6), "+v"(t##p##7));
#define TPIN_ALL  TPIN(0) TPIN(1) TPIN(2) TPIN(3) TPIN(4) TPIN(5) TPIN(6) TPIN(7)

// One wave (64 lanes = 64 z-states) per chain; blocks 0..255 forward,
// 256..511 backward. No LDS, no barriers.
//
// Round 10: depth-2 emission prefetch. Evidence: per step = 624 cyc, VALU
// issue accounts for ~290 -> ~330 stall cyc. FETCH_SIZE = 10.3 GB/dispatch
// vs 2.56 MB emit table: the 64 MB store stream continuously evicts emit
// from L2/L3, so e-gathers frequently miss to HBM (~900 cyc). The old
// 1-iteration prefetch gives only ~620 cyc slack -> ~300 cyc exposed per
// step (matches the stall). All VALU-side experiments (R3-R5: LDS bcast,
// bpermute, SGPR batching) were flat-or-worse, consistent with a memory-
// latency-bound chain. Fix: prefetch e TWO iterations ahead (~1240 cyc
// slack) via second shifted x-register sets. Numerics untouched.
__global__ __launch_bounds__(64, 1) void hmm_chains(
    const int*   __restrict__ inp,    // [SEQ, BATCH]
    const float* __restrict__ T,      // [ZD, ZD] row-major
    const float* __restrict__ pi,     // [ZD]
    const float* __restrict__ emit,   // [X, ZD]
    float* __restrict__ out_alpha,    // [SEQ, BATCH, ZD] fp32
    float* __restrict__ out_beta)     // [SEQ, BATCH, ZD] fp32
{
  const int lane = threadIdx.x;
  const int blk  = blockIdx.x;
  const bool fwd = (blk < BATCH);
  const int b    = fwd ? blk : blk - BATCH;

  REP64(TDECL)

  if (fwd) {
    // xvn[w] lane l = x[min(64w+l+1,511)]; xvn2[w] lane l = x[min(64w+l+2,511)].
    // In-iter: x[t+1] and x[t+2] are single readlanes at (w, idx).
    int xvn[8], xvn2[8];
    #pragma unroll
    for (int w = 0; w < 8; ++w) {
      int li1 = w * 64 + lane + 1; if (li1 > SEQ - 1) li1 = SEQ - 1;
      int li2 = w * 64 + lane + 2; if (li2 > SEQ - 1) li2 = SEQ - 1;
      xvn[w]  = inp[li1 * BATCH + b];
      xvn2[w] = inp[li2 * BATCH + b];
    }

    // alpha_t[l] = e_t[l] * sum_i alpha_{t-1}[i] * T[l][i]
    const float* Trp = T + lane * ZD;
    REP64(TLOADF)
    TPIN_ALL

    const int x0 = inp[b];                   // x[0], uniform scalar load
    float alpha = emit[x0 * ZD + lane] * pi[lane];
    float* op = out_alpha + (size_t)b * ZD + lane;
    *op = alpha;
    op += BATCH * ZD;

    // Prologue: fill the 2-deep e pipeline (e_cur = e_1, e_nx = e_2).
    const int x1 = lane_bcasti(xvn[0], 0);
    float e_cur = emit[x1 * ZD + lane];
    const int x2 = lane_bcasti(xvn2[0], 0);
    float e_nx  = emit[x2 * ZD + lane];

    #pragma unroll
    for (int w = 0; w < 8; ++w) {
      const int xn2w = xvn2[w];
      #pragma unroll 1                 // keep body inside L1I
      for (int idx = (w == 0) ? 1 : 0; idx < 64; ++idx) {
        const int   xt2  = lane_bcasti(xn2w, idx);  // x[t+2] (uniform, clamped)
        const float e_pf = emit[xt2 * ZD + lane];   // issued 2 iters before use
        float acc[4] = {0.f, 0.f, 0.f, 0.f};
        const float vbc = alpha;
        REP64(TFMA)                               // 64 readlane + 64 fma
        alpha = e_cur * ((acc[0] + acc[1]) + (acc[2] + acc[3]));
        *op = alpha;
        op += BATCH * ZD;
        e_cur = e_nx;
        e_nx  = e_pf;
      }
    }
  } else {
    // beta_t[l] = sum_j (e_{t+1}[j]*beta_{t+1}[j]) * T[j][l]
    // xvm[w] lane l = x[max(64w+l-1,0)] -> x[t-1] is a single readlane.
    int xvm[8];
    #pragma unroll
    for (int w = 0; w < 8; ++w) {
      int li = w * 64 + lane - 1; if (li < 0) li = 0;
      xvm[w] = inp[li * BATCH + b];
    }

    const float* Tcp = T + lane;
    REP64(TLOADB)
    TPIN_ALL

    float beta = 1.0f;
    float* op = out_beta + ((size_t)(SEQ - 1) * BATCH + b) * ZD + lane;
    *op = beta;
    op -= BATCH * ZD;

    // Prologue: 2-deep pipeline. e_next = e_511 (used at t=510),
    // e_n2 = e_510 (used at t=509). Uniform scalar loads for x[511], x[510].
    const int xL  = inp[(SEQ - 1) * BATCH + b];
    const int xL1 = inp[(SEQ - 2) * BATCH + b];
    float e_next = emit[xL  * ZD + lane];
    float e_n2   = emit[xL1 * ZD + lane];

    #pragma unroll
    for (int w = 7; w >= 0; --w) {
      const int xmw = xvm[w];
      #pragma unroll 1
      for (int idx = (w == 7) ? 62 : 63; idx >= 0; --idx) {
        const int   xtm  = lane_bcasti(xmw, idx); // x[t-1] (clamped at t=0)
        const float e_pf = emit[xtm * ZD + lane]; // used 2 iters later
        const float vbc  = e_next * beta;         // g[j] broadcast source
        float acc[4] = {0.f, 0.f, 0.f, 0.f};
        REP64(TFMA)
        beta = (acc[0] + acc[1]) + (acc[2] + acc[3]);
        *op = beta;
        op -= BATCH * ZD;
        e_next = e_n2;
        e_n2   = e_pf;
      }
    }
  }
}

// posterior[t,b,z] = alpha*beta / sum_z(alpha*beta). 8 z per lane, 8 lanes
// per (t,b) row, xor-shuffle reduction within the 8-lane group. 2-way ILP:
// each thread processes two independent row-groups (front/back half of the
// array) with all 8 float4 loads issued up front -> deeper MLP per wave.
// Per-row math and order identical to before (bit-identical outputs).
__global__ __launch_bounds__(256) void posterior_k(
    const float* __restrict__ a,
    const float* __restrict__ bt,
    float*       __restrict__ p)
{
  const int tid = blockIdx.x * 256 + threadIdx.x;
  const size_t base  = (size_t)tid * 8;
  const size_t base2 = base + (size_t)(SEQ / 2) * BATCH * ZD;

  const float4 va0 = *reinterpret_cast<const float4*>(a  + base);
  const float4 va1 = *reinterpret_cast<const float4*>(a  + base + 4);
  const float4 vb0 = *reinterpret_cast<const float4*>(bt + base);
  const float4 vb1 = *reinterpret_cast<const float4*>(bt + base + 4);
  const float4 wa0 = *reinterpret_cast<const float4*>(a  + base2);
  const float4 wa1 = *reinterpret_cast<const float4*>(a  + base2 + 4);
  const float4 wb0 = *reinterpret_cast<const float4*>(bt + base2);
  const float4 wb1 = *reinterpret_cast<const float4*>(bt + base2 + 4);

  const float p0 = va0.x * vb0.x, p1 = va0.y * vb0.y;
  const float p2 = va0.z * vb0.z, p3 = va0.w * vb0.w;
  const float p4 = va1.x * vb1.x, p5 = va1.y * vb1.y;
  const float p6 = va1.z * vb1.z, p7 = va1.w * vb1.w;

  const float q0 = wa0.x * wb0.x, q1 = wa0.y * wb0.y;
  const float q2 = wa0.z * wb0.z, q3 = wa0.w * wb0.w;
  const float q4 = wa1.x * wb1.x, q5 = wa1.y * wb1.y;
  const float q6 = wa1.z * wb1.z, q7 = wa1.w * wb1.w;

  float s = ((p0 + p1) + (p2 + p3)) + ((p4 + p5) + (p6 + p7));
  float u = ((q0 + q1) + (q2 + q3)) + ((q4 + q5) + (q6 + q7));
  s += __shfl_xor(s, 1);  u += __shfl_xor(u, 1);
  s += __shfl_xor(s, 2);  u += __shfl_xor(u, 2);
  s += __shfl_xor(s, 4);  u += __shfl_xor(u, 4);
  const float inv  = 1.0f / s;
  const float inv2 = 1.0f / u;

  float4 o0, o1, o2, o3;
  o0.x = p0 * inv;  o0.y = p1 * inv;  o0.z = p2 * inv;  o0.w = p3 * inv;
  o1.x = p4 * inv;  o1.y = p5 * inv;  o1.z = p6 * inv;  o1.w = p7 * inv;
  o2.x = q0 * inv2; o2.y = q1 * inv2; o2.z = q2 * inv2; o2.w = q3 * inv2;
  o3.x = q4 * inv2; o3.y = q5 * inv2; o3.z = q6 * inv2; o3.w = q7 * inv2;
  *reinterpret_cast<float4*>(p + base)      = o0;
  *reinterpret_cast<float4*>(p + base + 4)  = o1;
  *reinterpret_cast<float4*>(p + base2)     = o2;
  *reinterpret_cast<float4*>(p + base2 + 4) = o3;
}

extern "C" void kernel_launch(void* const* d_in, const int* in_sizes, int n_in,
                              void* d_out, int out_size, void* d_ws, size_t ws_size,
                              hipStream_t stream) {
  const int*   inp  = (const int*)  d_in[0];
  const float* T    = (const float*)d_in[1];
  const float* pi   = (const float*)d_in[2];
  const float* emit = (const float*)d_in[3];

  float* out = (float*)d_out;
  const size_t N = (size_t)SEQ * BATCH * ZD;   // 8388608 per output
  float* out_alpha = out;
  float* out_beta  = out + N;
  float* out_post  = out + 2 * N;

  hipLaunchKernelGGL(hmm_chains, dim3(2 * BATCH), dim3(64), 0, stream,
                     inp, T, pi, emit, out_alpha, out_beta);

  // Half the threads of before; each thread does two row-groups.
  hipLaunchKernelGGL(posterior_k, dim3((unsigned)(N / 2 / 2048)), dim3(256), 0, stream,
                     out_alpha, out_beta, out_post);
}